// Round 10
// baseline (1124.737 us; speedup 1.0000x reference)
//
#include <hip/hip_runtime.h>
#include <stdint.h>

#define LM1  127
#define NTHR 256

typedef _Float16 half8_t __attribute__((ext_vector_type(8)));
typedef _Float16 half4_t __attribute__((ext_vector_type(4)));
typedef float    f32x4   __attribute__((ext_vector_type(4)));

__device__ __forceinline__ float fast_tanh(float x) {
  float e = __expf(2.0f * x);
  return 1.0f - 2.0f * __builtin_amdgcn_rcpf(e + 1.0f);
}

// Round-10: sync-minimal design. 4 waves (1/SIMD), ONE barrier per substage.
//  - GEMM1 (swapped, h^T = W1^T @ z^T) computed REDUNDANTLY per wave from
//    REGISTER A-frags (wA, 64 VGPR) -- R5's failure was these frags living in
//    LDS (16 reads/wave); from regs the redundancy is MFMA-only (cheap).
//    Output packed into a PRIVATE per-wave hA via R5's verified bounce
//    (8x ds_write_b64 + lgkm + 4x ds_read_b128; within-wave, no barrier).
//  - GEMM2 (swapped, f^T = W2^T @ h^T): wave owns fcols [128w,128w+128),
//    8 M-tiles from register W2^T frags (wf, 128 VGPR; R8's verified layout).
//  - kc: R8's verified in-lane tanh + shfl_xor(16) c-quad combine.
//    h-map: fcol = 128w+16mt+4lq+reg = 8h+c -> h = 16w+2mt+(lq>>1),
//    c = 4(lq&1)+reg. After shfl both lql partners hold kcv[h]; writer =
//    (lql==0 && l15<4). zsbT garbage cols (l15>=4) stay zero forever.
//  - zsbT (R5/R8 layout) double-buffered; gds staged at s==3 for step i+1
//    (R5 flow) so the single end-of-substage barrier covers z AND gds.
// Cross-wave traffic per substage: zsbT only. Barriers: 1 (was 2).
#define BAR() asm volatile("s_waitcnt lgkmcnt(0)\n\ts_barrier" ::: "memory")

__global__ void __launch_bounds__(NTHR, 1) cde_kernel(
    const float* __restrict__ coeffs,
    const float* __restrict__ Wi1, const float* __restrict__ bi1,
    const float* __restrict__ Wi2, const float* __restrict__ bi2,
    const float* __restrict__ W1,  const float* __restrict__ b1,
    const float* __restrict__ W2,  const float* __restrict__ b2,
    float* __restrict__ out)
{
  __shared__ __align__(16) _Float16 zsbT[2][1024];   // 4 KB: z^T B-frag, dbuf
  __shared__ __align__(16) _Float16 hA[4][2048];     // 16 KB: per-wave h^T (private)
  __shared__ __align__(16) float    gds[2][3][4][8]; // dXdt at fr=0,.5,1 (dbuf)

  const int t    = threadIdx.x;
  const int lane = t & 63;
  const int w    = t >> 6;            // wave 0..3
  const int l15  = lane & 15;
  const int lq   = lane >> 4;
  const int lqh  = lq >> 1, lql = lq & 1;
  const int r4   = l15 & 3;
  const bool owner = (l15 < 4) && (lql == 0);
  const int row0 = blockIdx.x * 4;

  // zero zsbT (both buffers); cols l15>=4 stay zero forever
  for (int u = t; u < 1024; u += NTHR) ((uint32_t*)zsbT)[u] = 0u;

  // ---- GEMM1 A-frags in regs: W1^T, full 128 h (8 m-tiles x 2 kt)
  half8_t wA[8][2];
  #pragma unroll
  for (int m = 0; m < 8; ++m)
    #pragma unroll
    for (int kt = 0; kt < 2; ++kt)
      #pragma unroll
      for (int j = 0; j < 8; ++j)
        wA[m][kt][j] = (_Float16)W1[(1 + 32 * kt + 8 * lq + j) * 128 + 16 * m + l15];

  // u-constants per m-tile: hcols 16m+4lq+reg
  f32x4 w1t4[8], b14[8];
  #pragma unroll
  for (int m = 0; m < 8; ++m)
    #pragma unroll
    for (int reg = 0; reg < 4; ++reg) {
      w1t4[m][reg] = W1[16 * m + 4 * lq + reg];
      b14[m][reg]  = b1[16 * m + 4 * lq + reg];
    }

  // ---- GEMM2 A-frags in regs: W2^T, fcols [128w, 128w+128) (8 mt x 4 kt)
  half8_t wf[8][4];
  #pragma unroll
  for (int mt = 0; mt < 8; ++mt)
    #pragma unroll
    for (int kt = 0; kt < 4; ++kt)
      #pragma unroll
      for (int j = 0; j < 8; ++j)
        wf[mt][kt][j] =
            (_Float16)W2[(32 * kt + 8 * lq + j) * 512 + 128 * w + 16 * mt + l15];

  f32x4 b2v[8];
  #pragma unroll
  for (int mt = 0; mt < 8; ++mt)
    b2v[mt] = *(const f32x4*)&b2[128 * w + 16 * mt + 4 * lq];

  _Float16* const hAp = &hA[w][0];
  const int hbase = 8 * l15 + 4 * lql + 128 * lqh;   // + 256*m per m-tile (R5)

  // zsbT offsets per mt: h = 16w + 2mt + lqh, col = l15
  int zoffs[8];
  #pragma unroll
  for (int mt = 0; mt < 8; ++mt) {
    const int h = 16 * w + 2 * mt + lqh;
    zoffs[mt] = 512 * (h >> 5) + 128 * ((h >> 3) & 3) + 8 * l15 + (h & 7);
  }

  // ---- z0: each lane computes its 8 h-chains (h = 16w+2mt+lqh, batch r4)
  float z[8];
  {
    const float* cb = coeffs + (size_t)(row0 + r4) * (LM1 * 32);
    float x0[8];
    #pragma unroll
    for (int c = 0; c < 8; ++c) x0[c] = cb[c];
    float acc[8];
    #pragma unroll
    for (int mt = 0; mt < 8; ++mt) acc[mt] = bi2[16 * w + 2 * mt + lqh];
    for (int j = 0; j < 20; ++j) {
      float uj = bi1[j];
      #pragma unroll
      for (int c = 0; c < 8; ++c) uj += x0[c] * Wi1[c * 20 + j];
      uj = fmaxf(uj, 0.0f);
      #pragma unroll
      for (int mt = 0; mt < 8; ++mt) acc[mt] += uj * Wi2[j * 64 + 16 * w + 2 * mt + lqh];
    }
    #pragma unroll
    for (int mt = 0; mt < 8; ++mt) z[mt] = fast_tanh(acc[mt]);
  }
  if (owner) {
    #pragma unroll
    for (int mt = 0; mt < 8; ++mt) {
      zsbT[0][zoffs[mt]] = (_Float16)z[mt];
      out[(size_t)(row0 + l15) * 8192 + 16 * w + 2 * mt + lqh] = z[mt];
    }
  }

  // ---- coeff prefetch / gds staging on wave 3 (R5 flow)
  const int rg = (lane >> 3) & 3, cg = lane & 7;
  const float* cbp = coeffs + (size_t)(row0 + rg) * (LM1 * 32);
  const bool stg = (w == 3) && (lane < 32);
  float pb2 = 0.f, pc2 = 0.f, pd2 = 0.f, pbn2 = 0.f;
  if (stg) {
    const float pb = cbp[8 + cg], pc = cbp[16 + cg], pd = cbp[24 + cg], pbn = cbp[40 + cg];
    gds[0][0][rg][cg] = pb;
    gds[0][1][rg][cg] = pb + pc + 0.75f * pd;
    gds[0][2][rg][cg] = pbn;              // i=0 < LM1-1 always
  }

  __syncthreads();   // init complete (full barrier, once)

  for (int i = 0; i < LM1; ++i) {
    if (stg && i + 1 < LM1) {             // next-interval loads, in flight all step
      const float* nb = cbp + (size_t)(i + 1) * 32;
      pb2 = nb[8 + cg]; pc2 = nb[16 + cg]; pd2 = nb[24 + cg];
      pbn2 = (i + 2 < LM1) ? nb[40 + cg] : 0.0f;
    }

    float ksum[8];
    #pragma unroll
    for (int mt = 0; mt < 8; ++mt) ksum[mt] = 0.0f;

    #pragma unroll
    for (int s = 0; s < 4; ++s) {
      const int   rb = s & 1, wb = rb ^ 1;
      const int   gi = (s == 0) ? 0 : (s == 3) ? 2 : 1;
      const float ts = (float)i + ((s == 0) ? 0.0f : (s == 3) ? 1.0f : 0.5f);

      // z^T B-frags + dXdt (all reads of shared state, right after BAR)
      const half8_t zb0 = *(const half8_t*)(&zsbT[rb][8 * lane]);
      const half8_t zb1 = *(const half8_t*)(&zsbT[rb][512 + 8 * lane]);
      const f32x4 gv = *(const f32x4*)&gds[i & 1][gi][r4][4 * lql];

      // GEMM1 (redundant, from reg A-frags) + epilogue + private hA pack (R5)
      #pragma unroll
      for (int m = 0; m < 8; ++m) {
        f32x4 hd = {0.f, 0.f, 0.f, 0.f};
        hd = __builtin_amdgcn_mfma_f32_16x16x32_f16(wA[m][0], zb0, hd, 0, 0, 0);
        hd = __builtin_amdgcn_mfma_f32_16x16x32_f16(wA[m][1], zb1, hd, 0, 0, 0);
        half4_t hv;
        hv[0] = (_Float16)fmaxf(hd.x + fmaf(ts, w1t4[m].x, b14[m].x), 0.0f);
        hv[1] = (_Float16)fmaxf(hd.y + fmaf(ts, w1t4[m].y, b14[m].y), 0.0f);
        hv[2] = (_Float16)fmaxf(hd.z + fmaf(ts, w1t4[m].z, b14[m].z), 0.0f);
        hv[3] = (_Float16)fmaxf(hd.w + fmaf(ts, w1t4[m].w, b14[m].w), 0.0f);
        *(half4_t*)(hAp + hbase + 256 * m) = hv;
      }
      asm volatile("s_waitcnt lgkmcnt(0)" ::: "memory");  // within-wave hA handoff

      // GEMM2 (swapped, from reg A-frags) + fused kc
      half8_t hb[4];
      #pragma unroll
      for (int kt = 0; kt < 4; ++kt)
        hb[kt] = *(const half8_t*)(hAp + 512 * kt + 8 * lane);
      f32x4 d[8];
      #pragma unroll
      for (int mt = 0; mt < 8; ++mt) d[mt] = (f32x4){0.f, 0.f, 0.f, 0.f};
      #pragma unroll
      for (int kt = 0; kt < 4; ++kt)
        #pragma unroll
        for (int mt = 0; mt < 8; ++mt)
          d[mt] = __builtin_amdgcn_mfma_f32_16x16x32_f16(wf[mt][kt], hb[kt], d[mt], 0, 0, 0);

      const float wgt = (s == 1 || s == 2) ? 2.0f : 1.0f;
      const float cn  = (s == 2) ? 1.0f : 0.5f;
      #pragma unroll
      for (int mt = 0; mt < 8; ++mt) {
        float p = fast_tanh(d[mt].x + b2v[mt].x) * gv.x
                + fast_tanh(d[mt].y + b2v[mt].y) * gv.y
                + fast_tanh(d[mt].z + b2v[mt].z) * gv.z
                + fast_tanh(d[mt].w + b2v[mt].w) * gv.w;
        const float kcv = p + __shfl_xor(p, 16, 64);   // combine c-quads (lql pair)
        ksum[mt] += wgt * kcv;
        if (s < 3) {
          if (owner) zsbT[wb][zoffs[mt]] = (_Float16)fmaf(cn, kcv, z[mt]);
        } else {
          z[mt] = fmaf(ksum[mt], 1.0f / 6.0f, z[mt]);
          if (owner) {
            zsbT[wb][zoffs[mt]] = (_Float16)z[mt];
            out[(size_t)(row0 + l15) * 8192 + (size_t)(i + 1) * 64
                + 16 * w + 2 * mt + lqh] = z[mt];   // fire-and-forget
          }
        }
      }
      if (s == 3 && stg && i + 1 < LM1) {  // stage gds for step i+1 (other parity)
        const int ii = i + 1;
        gds[ii & 1][0][rg][cg] = pb2;
        gds[ii & 1][1][rg][cg] = pb2 + pc2 + 0.75f * pd2;
        gds[ii & 1][2][rg][cg] =
            (ii < LM1 - 1) ? pbn2 : fmaf(3.0f, pd2, fmaf(2.0f, pc2, pb2));
      }
      BAR();   // the single per-substage barrier (lgkm-only)
    }
  }
}

extern "C" void kernel_launch(void* const* d_in, const int* in_sizes, int n_in,
                              void* d_out, int out_size, void* d_ws, size_t ws_size,
                              hipStream_t stream) {
  const float* coeffs = (const float*)d_in[0];
  const float* Wi1    = (const float*)d_in[1];
  const float* bi1    = (const float*)d_in[2];
  const float* Wi2    = (const float*)d_in[3];
  const float* bi2    = (const float*)d_in[4];
  const float* W1     = (const float*)d_in[5];
  const float* b1     = (const float*)d_in[6];
  const float* W2     = (const float*)d_in[7];
  const float* b2     = (const float*)d_in[8];
  float* out          = (float*)d_out;
  (void)in_sizes; (void)n_in; (void)out_size; (void)d_ws; (void)ws_size;
  cde_kernel<<<256, NTHR, 0, stream>>>(coeffs, Wi1, bi1, Wi2, bi2,
                                       W1, b1, W2, b2, out);
}

// Round 11
// 540.524 us; speedup vs baseline: 2.0808x; 2.0808x over previous
//
#include <hip/hip_runtime.h>
#include <stdint.h>

#define LM1  127
#define NTHR 512

typedef _Float16 half8_t __attribute__((ext_vector_type(8)));
typedef float    f32x4   __attribute__((ext_vector_type(4)));

__device__ __forceinline__ float fast_tanh(float x) {
  float e = __expf(2.0f * x);
  return 1.0f - 2.0f * __builtin_amdgcn_rcpf(e + 1.0f);
}

// FINAL (round 11): revert to the round-3 champion (498 us kernel time).
// Ten structurally distinct redesigns (R1/R5/R6/R8/R9/R10 + barrier/shuffle/
// wave-count variants R0/R2/R3) bracket a structural floor at ~2350 cyc per
// RK4 sub-stage for this serial-chain problem:
//   - per-SIMD MFMA ~576 cyc (144 MFMA/CU, M=16 tiles padded from 4 real rows)
//   - per-SIMD VALU ~672 cyc (kc tanh + epilogues + addressing)
//   - CU-wide LDS pipe ~900 cyc (z/h staging + fwb handoff)
//   - 2 lockstep barriers + exposed dep latency
// Attempts to trade between these (redundant GEMM1: R5/R10; fewer waves:
// R1/R6; in-register kc: R8; co-resident blocks: R9) all regressed because
// per-block work is fixed by the padded network dims, the integration chain
// is irreducibly serial, and lockstep phases burst-serialize each resource.
// Structure: 8 waves dual-role; lgkm-only barriers (global stores fire-and-
// forget, coeff prefetch stays in flight); phase B = GEMM1 h-tile/wave;
// phase C = GEMM2 4 n-tiles/wave + fwb handoff + in-lane kc with one
// v_permlane32_swap combine.
#define BAR() asm volatile("s_waitcnt lgkmcnt(0)\n\ts_barrier" ::: "memory")

__global__ void __launch_bounds__(NTHR, 2) cde_kernel(
    const float* __restrict__ coeffs,
    const float* __restrict__ Wi1, const float* __restrict__ bi1,
    const float* __restrict__ Wi2, const float* __restrict__ bi2,
    const float* __restrict__ W1,  const float* __restrict__ b1,
    const float* __restrict__ W2,  const float* __restrict__ b2,
    float* __restrict__ out)
{
  __shared__ __align__(16) _Float16 zsb[1024];       // 2 KB: chunk = kh*64 + lq*16 + m
  __shared__ __align__(16) _Float16 hA [2048];       // 4 KB: chunk = kt*64 + lq*16 + m
  __shared__ __align__(16) float    fwb[8][288];     // 9 KB: word(cl,r) = 36*(cl>>3)+4*(cl&7)+r
  __shared__ __align__(16) float    gds[2][3][4][8]; // double-buffered dXdt at fr=0,0.5,1

  const int t    = threadIdx.x;
  const int lane = t & 63;
  const int w    = t >> 6;            // wave 0..7
  const int l15  = lane & 15;
  const int lq   = lane >> 4;
  const int row0 = blockIdx.x * 4;

  // zero chunk buffers once (rows m>=4 stay zero)
  for (int u = t; u < 512;  u += NTHR) ((uint32_t*)zsb)[u] = 0u;
  for (int u = t; u < 1024; u += NTHR) ((uint32_t*)hA)[u]  = 0u;

  // ---- W1 -> B-fragments (all waves; wave w owns h-cols [16w,16w+16))
  half8_t bB[2];
  #pragma unroll
  for (int kt = 0; kt < 2; ++kt)
    #pragma unroll
    for (int j = 0; j < 8; ++j)
      bB[kt][j] = (_Float16)W1[(1 + kt * 32 + lq * 8 + j) * 128 + w * 16 + l15];
  const float w1t_c = W1[w * 16 + l15];
  const float b1_c  = b1[w * 16 + l15];
  _Float16* hwp;                      // hA write base (phase-B epilogue, lanes<16)
  {
    const int col = 16 * w + l15;
    const int ktw = (col >> 5) & 3, lqw2 = (col >> 3) & 3, j2 = col & 7;
    hwp = &hA[8 * (ktw * 64 + lqw2 * 16) + j2];
  }

  // ---- W2 -> B-fragments: 4 n-tiles x 4 k-tiles (cols 64w + nt*16 + l15)
  half8_t bf[4][4];
  #pragma unroll
  for (int nt = 0; nt < 4; ++nt)
    #pragma unroll
    for (int kt = 0; kt < 4; ++kt)
      #pragma unroll
      for (int j = 0; j < 8; ++j)
        bf[nt][kt][j] =
            (_Float16)W2[(kt * 32 + lq * 8 + j) * 512 + w * 64 + nt * 16 + l15];

  // ---- kc constants: lane = cp*32 + hh*4 + r, in-lane c = 4cp+cc
  const int r_ = lane & 3;
  const int hh = (lane >> 2) & 7;
  const int cp = lane >> 5;
  const float* bp = b2 + w * 64 + hh * 8 + cp * 4;
  const float b2c0 = bp[0], b2c1 = bp[1], b2c2 = bp[2], b2c3 = bp[3];
  const int frbase = 36 * hh + 16 * cp + r_;   // fwb word for (cl = 8hh+4cp, row r_)
  const int hx = 8 * w + hh;                   // owner h-col (lanes 0..31)

  _Float16* zwp;                               // zsb write slot for this owner
  {
    const int kh = hx >> 5, lqw = (hx >> 3) & 3, jj = hx & 7;
    zwp = &zsb[8 * (kh * 64 + lqw * 16 + r_) + jj];
  }
  float* const fsp = &fwb[w][36 * (l15 >> 3) + 4 * (l15 & 7)];  // D store base (+72*nt)

  // ---- z0 (owners: lanes 0..31 of each wave)
  float z = 0.0f;
  if (lane < 32) {
    const float* cb = coeffs + (size_t)(row0 + r_) * (LM1 * 32);
    float x0[8];
    #pragma unroll
    for (int c = 0; c < 8; ++c) x0[c] = cb[c];
    float acc = bi2[hx];
    for (int j = 0; j < 20; ++j) {
      float u = bi1[j];
      #pragma unroll
      for (int c = 0; c < 8; ++c) u += x0[c] * Wi1[c * 20 + j];
      acc += fmaxf(u, 0.0f) * Wi2[j * 64 + hx];
    }
    z = fast_tanh(acc);
    out[(size_t)(row0 + r_) * 8192 + hx] = z;
  }

  // ---- coeff prefetch on wave 7: rg = (lane>>3)&3, cg = lane&7
  const int rg = (lane >> 3) & 3, cg = lane & 7;
  const float* cbp = coeffs + (size_t)(row0 + rg) * (LM1 * 32);
  float pb = 0.f, pc = 0.f, pd = 0.f, pbn = 0.f;
  const bool stg = (w == 7) && (lane < 32);
  if (stg) { pb = cbp[8 + cg]; pc = cbp[16 + cg]; pd = cbp[24 + cg]; pbn = cbp[40 + cg]; }

  __syncthreads();   // init-zero + weight staging complete (full barrier, once)

  for (int i = 0; i < LM1; ++i) {
    if (stg) {
      gds[i & 1][0][rg][cg] = pb;
      gds[i & 1][1][rg][cg] = pb + pc + 0.75f * pd;
      gds[i & 1][2][rg][cg] = (i < LM1 - 1) ? pbn : fmaf(3.0f, pd, fmaf(2.0f, pc, pb));
      if (i + 1 < LM1) {
        const float* nb = cbp + (size_t)(i + 1) * 32;
        pb = nb[8 + cg]; pc = nb[16 + cg]; pd = nb[24 + cg];
        pbn = (i + 2 < LM1) ? nb[40 + cg] : 0.0f;
      }
    }

    float ksum = 0.0f, kprev = 0.0f;
    #pragma unroll
    for (int s = 0; s < 4; ++s) {
      const float coef = (s == 0) ? 0.0f : (s == 3) ? 1.0f : 0.5f;
      const float ts   = (float)i + ((s == 0) ? 0.0f : (s == 3) ? 1.0f : 0.5f);
      const int   gi   = (s == 0) ? 0 : (s == 3) ? 2 : 1;

      // Phase A: owners stage zs
      if (lane < 32) *zwp = (_Float16)(z + coef * kprev);
      BAR();   // lgkm-only barrier: zsb (+ gds at s=0) visible; vmem stays in flight

      // Phase B (all waves): h-tile w, reads at 8*lane halfs (conflict-free)
      {
        const half8_t a0 = *(const half8_t*)(zsb + 8 * lane);
        const half8_t a1 = *(const half8_t*)(zsb + 512 + 8 * lane);
        f32x4 hd = {0.f, 0.f, 0.f, 0.f};
        hd = __builtin_amdgcn_mfma_f32_16x16x32_f16(a0, bB[0], hd, 0, 0, 0);
        hd = __builtin_amdgcn_mfma_f32_16x16x32_f16(a1, bB[1], hd, 0, 0, 0);
        if (lane < 16) {
          const float hb = fmaf(ts, w1t_c, b1_c);
          hwp[0]  = (_Float16)fmaxf(hd.x + hb, 0.0f);
          hwp[8]  = (_Float16)fmaxf(hd.y + hb, 0.0f);
          hwp[16] = (_Float16)fmaxf(hd.z + hb, 0.0f);
          hwp[24] = (_Float16)fmaxf(hd.w + hb, 0.0f);
        }
      }
      BAR();   // lgkm-only barrier: hA visible

      // Phase C (all waves): f-cols [64w, 64w+64), then kc epilogue
      {
        // hoist the dXdt read: depends only on (i, s), not on the MFMA chain
        const f32x4 gv = *(const f32x4*)&gds[i & 1][gi][r_][4 * cp];

        half8_t ha[4];
        #pragma unroll
        for (int kt = 0; kt < 4; ++kt)
          ha[kt] = *(const half8_t*)(hA + 8 * lane + 512 * kt);
        f32x4 d0 = {0.f, 0.f, 0.f, 0.f}, d1 = d0, d2 = d0, d3 = d0;
        #pragma unroll
        for (int kt = 0; kt < 4; ++kt) {
          d0 = __builtin_amdgcn_mfma_f32_16x16x32_f16(ha[kt], bf[0][kt], d0, 0, 0, 0);
          d1 = __builtin_amdgcn_mfma_f32_16x16x32_f16(ha[kt], bf[1][kt], d1, 0, 0, 0);
          d2 = __builtin_amdgcn_mfma_f32_16x16x32_f16(ha[kt], bf[2][kt], d2, 0, 0, 0);
          d3 = __builtin_amdgcn_mfma_f32_16x16x32_f16(ha[kt], bf[3][kt], d3, 0, 0, 0);
        }
        if (lane < 16) {
          *(f32x4*)(fsp)       = d0;
          *(f32x4*)(fsp + 72)  = d1;
          *(f32x4*)(fsp + 144) = d2;
          *(f32x4*)(fsp + 216) = d3;
        }
        asm volatile("s_waitcnt lgkmcnt(0)" ::: "memory");  // within-wave handoff

        // kc: 4 in-lane channels; cross-half combine on the VALU pipe
        const float* fb = &fwb[w][frbase];
        const float v0 = fb[0], v1 = fb[4], v2 = fb[8], v3 = fb[12];
        float kcv = fast_tanh(v0 + b2c0) * gv.x + fast_tanh(v1 + b2c1) * gv.y
                  + fast_tanh(v2 + b2c2) * gv.z + fast_tanh(v3 + b2c3) * gv.w;
        {
          int a = __float_as_int(kcv), b;
          asm volatile("v_mov_b32 %1, %0\n\t"
                       "v_permlane32_swap_b32 %0, %1"
                       : "+v"(a), "=&v"(b));
          kcv = __int_as_float(a) + __int_as_float(b);
        }
        kprev = kcv;
        ksum += ((s == 1 || s == 2) ? 2.0f : 1.0f) * kcv;
      }
    }
    if (lane < 32) {
      z += ksum * (1.0f / 6.0f);
      out[(size_t)(row0 + r_) * 8192 + (size_t)(i + 1) * 64 + hx] = z;  // fire-and-forget
    }
  }
}

extern "C" void kernel_launch(void* const* d_in, const int* in_sizes, int n_in,
                              void* d_out, int out_size, void* d_ws, size_t ws_size,
                              hipStream_t stream) {
  const float* coeffs = (const float*)d_in[0];
  const float* Wi1    = (const float*)d_in[1];
  const float* bi1    = (const float*)d_in[2];
  const float* Wi2    = (const float*)d_in[3];
  const float* bi2    = (const float*)d_in[4];
  const float* W1     = (const float*)d_in[5];
  const float* b1     = (const float*)d_in[6];
  const float* W2     = (const float*)d_in[7];
  const float* b2     = (const float*)d_in[8];
  float* out          = (float*)d_out;
  (void)in_sizes; (void)n_in; (void)out_size; (void)d_ws; (void)ws_size;
  cde_kernel<<<256, NTHR, 0, stream>>>(coeffs, Wi1, bi1, Wi2, bi2,
                                       W1, b1, W2, b2, out);
}